// Round 1
// 502.733 us; speedup vs baseline: 1.0608x; 1.0608x over previous
//
#include <hip/hip_runtime.h>

typedef float f32x4 __attribute__((ext_vector_type(4)));

// Problem constants (from setup_inputs): B=32, N=8, Lq=256, Ld=512, D=768
#define BB 32
#define NN 8
#define LQ 256
#define LD 512
#define DD 768
#define D4 (DD / 4)                   // 192 float4 per row

#define QCH 8                         // lq chunks in qsum kernel
#define QROWS (LQ / QCH)              // 32 rows per chunk
#define QPART_ELEMS (QCH * BB * DD)   // 196608 floats (~786 KB) in ws

#define CH 16                         // l-chunks per (b,n) doc in docs kernel
#define LCHUNK (LD / CH)              // 32 rows per block
#define NBLK (BB * NN * CH)           // 4096 doc blocks -> 10 resident blocks/CU (30 waves)

// ---------------------------------------------------------------------------
// Kernel 1: qpart[c][b][:] = sum of 32 lq rows. 192 threads; thread t owns
// float4 column t. Nontemporal loads (q has zero reuse -> don't allocate in
// L2/L3, don't force eviction of the poison fill's dirty lines). 8 independent
// accumulator chains for MLP. grid (32, 8) x 192.
// ---------------------------------------------------------------------------
__global__ void __launch_bounds__(192)
qsum_kernel(const float* __restrict__ q, float* __restrict__ qpart) {
    int b = blockIdx.x;               // 0..31
    int c = blockIdx.y;               // 0..7 lq chunk
    int t = threadIdx.x;              // 0..191 float4 column

    const f32x4* p = (const f32x4*)(q + ((size_t)b * LQ + (size_t)c * QROWS) * DD) + t;

    f32x4 z = {0.f, 0.f, 0.f, 0.f};
    f32x4 acc[8];
#pragma unroll
    for (int i = 0; i < 8; ++i) acc[i] = z;

#pragma unroll
    for (int i = 0; i < QROWS; ++i)           // fully unrolled: static acc index
        acc[i & 7] += __builtin_nontemporal_load(p + (size_t)i * D4);

    f32x4 r = ((acc[0] + acc[1]) + (acc[2] + acc[3])) +
              ((acc[4] + acc[5]) + (acc[6] + acc[7]));
    ((f32x4*)qpart)[((size_t)c * BB + b) * D4 + t] = r;   // cached store: reused 4096x
}

// ---------------------------------------------------------------------------
// Kernel 2: stream docs exactly once. Block = (bn, l-chunk of 32 rows),
// 192 threads = 3 waves; thread t owns float4 column t.
// Prologue sums the 8 qpart fragments (cached loads -- qpart IS reused).
// Main loop: 32 nontemporal float4 loads in 8-deep batches, 8 independent
// accumulator chains. One store per block.
// ---------------------------------------------------------------------------
__global__ void __launch_bounds__(192)
docs_kernel(const float* __restrict__ docs, const int* __restrict__ is_ans,
            const float* __restrict__ qpart, float* __restrict__ partials) {
    int bn    = blockIdx.x / CH;      // 0 .. 255
    int chunk = blockIdx.x - bn * CH; // 0 .. 15
    int b     = bn >> 3;              // bn / N
    int t     = threadIdx.x;          // 0 .. 191

    f32x4 qv = {0.f, 0.f, 0.f, 0.f};
#pragma unroll
    for (int c = 0; c < QCH; ++c)
        qv += ((const f32x4*)qpart)[((size_t)c * BB + b) * D4 + t];

    const f32x4* p = (const f32x4*)(docs + ((size_t)bn * LD + (size_t)chunk * LCHUNK) * DD) + t;

    f32x4 z = {0.f, 0.f, 0.f, 0.f};
    f32x4 acc[8];
#pragma unroll
    for (int i = 0; i < 8; ++i) acc[i] = z;

#pragma unroll
    for (int l0 = 0; l0 < LCHUNK; l0 += 8) {
        f32x4 v[8];
#pragma unroll
        for (int k = 0; k < 8; ++k)
            v[k] = __builtin_nontemporal_load(p + (size_t)(l0 + k) * D4);
#pragma unroll
        for (int k = 0; k < 8; ++k)
            acc[k] += v[k] * qv;
    }

    f32x4 r = ((acc[0] + acc[1]) + (acc[2] + acc[3])) +
              ((acc[4] + acc[5]) + (acc[6] + acc[7]));
    float s = r.x + r.y + r.z + r.w;

    // wave-64 reduce
    for (int off = 32; off > 0; off >>= 1)
        s += __shfl_down(s, off, 64);

    __shared__ float wsum[3];
    if ((t & 63) == 0) wsum[t >> 6] = s;
    __syncthreads();
    if (t == 0) {
        float sign = is_ans[bn] ? -1.f : 1.f;
        partials[blockIdx.x] = (wsum[0] + wsum[1] + wsum[2]) * sign;
    }
}

// ---------------------------------------------------------------------------
// Kernel 3: reduce 4096 per-block partials, apply 1/(Lq*Ld)
// ---------------------------------------------------------------------------
__global__ void __launch_bounds__(256)
finish_kernel(const float* __restrict__ partials, float* __restrict__ out) {
    int t = threadIdx.x;
    float s = 0.f;
#pragma unroll
    for (int i = 0; i < NBLK; i += 256)
        s += partials[i + t];
    for (int off = 32; off > 0; off >>= 1)
        s += __shfl_down(s, off, 64);
    __shared__ float wsum[4];
    if ((t & 63) == 0) wsum[t >> 6] = s;
    __syncthreads();
    if (t == 0)
        out[0] = (wsum[0] + wsum[1] + wsum[2] + wsum[3]) * (1.f / ((float)LQ * (float)LD));
}

extern "C" void kernel_launch(void* const* d_in, const int* in_sizes, int n_in,
                              void* d_out, int out_size, void* d_ws, size_t ws_size,
                              hipStream_t stream) {
    const float* q      = (const float*)d_in[0];   // [B, Lq, D] f32
    const float* docs   = (const float*)d_in[1];   // [B, N, Ld, D] f32
    const int*   is_ans = (const int*)d_in[2];     // [B, N] bool -> int
    float* out = (float*)d_out;

    float* qpart    = (float*)d_ws;                // [QCH*B*D]
    float* partials = qpart + QPART_ELEMS;         // [NBLK]

    qsum_kernel<<<dim3(BB, QCH), 192, 0, stream>>>(q, qpart);
    docs_kernel<<<dim3(NBLK), 192, 0, stream>>>(docs, is_ans, qpart, partials);
    finish_kernel<<<1, 256, 0, stream>>>(partials, out);
}